// Round 6
// baseline (456.127 us; speedup 1.0000x reference)
//
#include <hip/hip_runtime.h>
#include <math.h>

#define PI2_6f 1.64493406684822643647f
#define LN2f   0.69314718055994530942f

// clang-native 4-float vector: accepted by __builtin_nontemporal_store,
// lowers to global_store_dwordx4 nt.
typedef float vfloat4 __attribute__((ext_vector_type(4)));

// fast ln(x): single v_log_f32 (log2) * ln2. ~1 ulp of log2.
__device__ __forceinline__ float fast_log(float x) {
    return __builtin_amdgcn_logf(x) * LN2f;
}

// fast 1/x: single v_rcp_f32, ~1 ulp.
__device__ __forceinline__ float fast_rcp(float x) {
    return __builtin_amdgcn_rcpf(x);
}

__device__ __forceinline__ float polevlA(float w) {
    float y = 4.65128586073990045278e-5f;
    y = fmaf(y, w, 7.31589045238094711071e-3f);
    y = fmaf(y, w, 1.33847639578309018650e-1f);
    y = fmaf(y, w, 8.79691311754530315341e-1f);
    y = fmaf(y, w, 2.71149851196553469920e0f);
    y = fmaf(y, w, 4.25697156008121755724e0f);
    y = fmaf(y, w, 3.29771340985225106936e0f);
    y = fmaf(y, w, 1.00000000000000000126e0f);
    return y;
}

__device__ __forceinline__ float polevlB(float w) {
    float y = 6.90990488912553276999e-4f;
    y = fmaf(y, w, 2.54043763932544379113e-2f);
    y = fmaf(y, w, 2.82974860602568089943e-1f);
    y = fmaf(y, w, 1.41172597751831069617e0f);
    y = fmaf(y, w, 3.63800533345137075418e0f);
    y = fmaf(y, w, 5.03278880143316990390e0f);
    y = fmaf(y, w, 4.92478529773146006102e0f);
    y = fmaf(y, w, 1.00000000000000000000e0f);
    return y;
}

__device__ __forceinline__ float spencef(float x) {
    // Range reduction (branchless, mirrors Cephes/reference semantics).
    // `hi` implies !big so xt==x there; `big` needs 1/x. One rcp serves both.
    const float r = fast_rcp(x);              // inf at x==0, unused there
    const bool big = x > 2.0f;
    const float xt = big ? r : x;
    const bool hi = xt > 1.5f;                // only possible when !big
    const bool lo = xt < 0.5f;

    float w = xt - 1.0f;
    w = lo ? -xt : w;
    w = hi ? (r - 1.0f) : w;                  // 1/xt - 1 == r - 1 when hi

    const float y_poly = -w * polevlA(w) * fast_rcp(polevlB(w));

    const float log_xt   = fast_log(xt > 0.0f ? xt : 1.0f);
    const float log_1mxt = fast_log(xt < 1.0f ? 1.0f - xt : 1.0f);

    // flag1 correction (lo), then flag2 correction (big|hi), as in Cephes
    float y = y_poly;
    y = lo ? (PI2_6f - log_xt * log_1mxt - y) : y;
    y = (big || hi) ? (-0.5f * log_xt * log_xt - y) : y;

    // exact special points / domain
    y = (x == 0.0f) ? PI2_6f : y;
    y = (x == 1.0f) ? 0.0f : y;
    y = (x < 0.0f) ? __int_as_float(0x7fc00000) : y;  // NaN
    return y;
}

__device__ __forceinline__ vfloat4 spence4(vfloat4 v) {
    vfloat4 o;
    o.x = spencef(v.x);
    o.y = spencef(v.y);
    o.z = spencef(v.z);
    o.w = spencef(v.w);
    return o;
}

__global__ void __launch_bounds__(256)
spence_kernel(const vfloat4* __restrict__ in, vfloat4* __restrict__ out, int n4) {
    const int T = gridDim.x * blockDim.x;
    int i = blockIdx.x * blockDim.x + threadIdx.x;
    // Batched: 4 independent, fully-coalesced 16B loads in flight per thread.
    for (; i + 3 * T < n4; i += 4 * T) {
        const vfloat4 a = in[i];
        const vfloat4 b = in[i + T];
        const vfloat4 c = in[i + 2 * T];
        const vfloat4 d = in[i + 3 * T];
        const vfloat4 oa = spence4(a);
        const vfloat4 ob = spence4(b);
        const vfloat4 oc = spence4(c);
        const vfloat4 od = spence4(d);
        // Output is never re-read: non-temporal stores avoid evicting the
        // L2/L3-resident input.
        __builtin_nontemporal_store(oa, &out[i]);
        __builtin_nontemporal_store(ob, &out[i + T]);
        __builtin_nontemporal_store(oc, &out[i + 2 * T]);
        __builtin_nontemporal_store(od, &out[i + 3 * T]);
    }
    for (; i < n4; i += T) {
        __builtin_nontemporal_store(spence4(in[i]), &out[i]);
    }
}

__global__ void __launch_bounds__(256)
spence_tail_kernel(const float* __restrict__ in, float* __restrict__ out,
                   int start, int n) {
    const int i = start + blockIdx.x * blockDim.x + threadIdx.x;
    if (i < n) out[i] = spencef(in[i]);
}

extern "C" void kernel_launch(void* const* d_in, const int* in_sizes, int n_in,
                              void* d_out, int out_size, void* d_ws, size_t ws_size,
                              hipStream_t stream) {
    const float* in = (const float*)d_in[0];
    float* out = (float*)d_out;
    const int n = in_sizes[0];
    const int n4 = n / 4;

    const int block = 256;
    // One 4-wide batch per thread covers the whole array (n4=16Mi -> 16384 blocks).
    long long want = ((long long)n4 + 4LL * block - 1) / (4LL * block);
    int grid = (int)(want < 1 ? 1 : (want > 65535 ? 65535 : want));

    spence_kernel<<<grid, block, 0, stream>>>(
        (const vfloat4*)in, (vfloat4*)out, n4);

    const int tail_start = n4 * 4;
    const int tail = n - tail_start;
    if (tail > 0) {
        spence_tail_kernel<<<(tail + block - 1) / block, block, 0, stream>>>(
            in, out, tail_start, n);
    }
}

// Round 9
// 437.290 us; speedup vs baseline: 1.0431x; 1.0431x over previous
//
#include <hip/hip_runtime.h>
#include <math.h>

#define PI2_6f 1.64493406684822643647f
#define LN2f   0.69314718055994530942f

typedef float vfloat4 __attribute__((ext_vector_type(4)));

// fast ln(x): single v_log_f32 (log2) * ln2. ~1 ulp of log2.
__device__ __forceinline__ float fast_log(float x) {
    return __builtin_amdgcn_logf(x) * LN2f;
}

// fast 1/x: single v_rcp_f32, ~1 ulp.
__device__ __forceinline__ float fast_rcp(float x) {
    return __builtin_amdgcn_rcpf(x);
}

__device__ __forceinline__ float polevlA(float w) {
    float y = 4.65128586073990045278e-5f;
    y = fmaf(y, w, 7.31589045238094711071e-3f);
    y = fmaf(y, w, 1.33847639578309018650e-1f);
    y = fmaf(y, w, 8.79691311754530315341e-1f);
    y = fmaf(y, w, 2.71149851196553469920e0f);
    y = fmaf(y, w, 4.25697156008121755724e0f);
    y = fmaf(y, w, 3.29771340985225106936e0f);
    y = fmaf(y, w, 1.00000000000000000126e0f);
    return y;
}

__device__ __forceinline__ float polevlB(float w) {
    float y = 6.90990488912553276999e-4f;
    y = fmaf(y, w, 2.54043763932544379113e-2f);
    y = fmaf(y, w, 2.82974860602568089943e-1f);
    y = fmaf(y, w, 1.41172597751831069617e0f);
    y = fmaf(y, w, 3.63800533345137075418e0f);
    y = fmaf(y, w, 5.03278880143316990390e0f);
    y = fmaf(y, w, 4.92478529773146006102e0f);
    y = fmaf(y, w, 1.00000000000000000000e0f);
    return y;
}

__device__ __forceinline__ float spencef(float x) {
    // Range reduction (branchless, mirrors Cephes/reference semantics).
    // `hi` implies !big so xt==x there; `big` needs 1/x. One rcp serves both.
    const float r = fast_rcp(x);              // inf at x==0, unused there
    const bool big = x > 2.0f;
    const float xt = big ? r : x;
    const bool hi = xt > 1.5f;                // only possible when !big
    const bool lo = xt < 0.5f;                // note: big implies lo (1/x < 0.5)

    float w = xt - 1.0f;
    w = lo ? -xt : w;
    w = hi ? (r - 1.0f) : w;                  // 1/xt - 1 == r - 1 when hi

    const float y_poly = -w * polevlA(w) * fast_rcp(polevlB(w));

    // Unguarded logs: x==0 -> log(0)=-inf -> NaN, overridden by x==0 select;
    // x<0 -> log(neg)=NaN, overridden to NaN anyway; hi/big region never
    // consumes log_1mxt (cndmask isolates the unselected NaN operand).
    const float log_xt   = fast_log(xt);
    const float log_1mxt = fast_log(1.0f - xt);

    // flag1 correction (lo), then flag2 correction (big|hi), as in Cephes
    float y = y_poly;
    y = lo ? (PI2_6f - log_xt * log_1mxt - y) : y;
    y = (big || hi) ? (-0.5f * log_xt * log_xt - y) : y;

    // exact special points / domain
    y = (x == 0.0f) ? PI2_6f : y;
    y = (x == 1.0f) ? 0.0f : y;
    y = (x < 0.0f) ? __int_as_float(0x7fc00000) : y;  // NaN
    return y;
}

__device__ __forceinline__ vfloat4 spence4(vfloat4 v) {
    vfloat4 o;
    o.x = spencef(v.x);
    o.y = spencef(v.y);
    o.z = spencef(v.z);
    o.w = spencef(v.w);
    return o;
}

__global__ void __launch_bounds__(256)
spence_kernel(const vfloat4* __restrict__ in, vfloat4* __restrict__ out, int n4) {
    const int T = gridDim.x * blockDim.x;
    int i = blockIdx.x * blockDim.x + threadIdx.x;
    for (; i + 3 * T < n4; i += 4 * T) {
        const vfloat4 a = in[i];
        const vfloat4 b = in[i + T];
        const vfloat4 c = in[i + 2 * T];
        const vfloat4 d = in[i + 3 * T];
        // Pin the 4 loads before any compute: the compiler may not sink them
        // past this barrier, so all 4 stay in flight (vmcnt(3..0) per use)
        // and HBM latency hides under the ~400-cycle ALU chain.
        __builtin_amdgcn_sched_barrier(0);
        out[i]         = spence4(a);
        out[i + T]     = spence4(b);
        out[i + 2 * T] = spence4(c);
        out[i + 3 * T] = spence4(d);
    }
    for (; i < n4; i += T) {
        out[i] = spence4(in[i]);
    }
}

__global__ void __launch_bounds__(256)
spence_tail_kernel(const float* __restrict__ in, float* __restrict__ out,
                   int start, int n) {
    const int i = start + blockIdx.x * blockDim.x + threadIdx.x;
    if (i < n) out[i] = spencef(in[i]);
}

extern "C" void kernel_launch(void* const* d_in, const int* in_sizes, int n_in,
                              void* d_out, int out_size, void* d_ws, size_t ws_size,
                              hipStream_t stream) {
    const float* in = (const float*)d_in[0];
    float* out = (float*)d_out;
    const int n = in_sizes[0];
    const int n4 = n / 4;

    const int block = 256;
    // One 4-wide batch per thread covers the whole array (n4=16Mi -> 16384 blocks).
    long long want = ((long long)n4 + 4LL * block - 1) / (4LL * block);
    int grid = (int)(want < 1 ? 1 : (want > 65535 ? 65535 : want));

    spence_kernel<<<grid, block, 0, stream>>>(
        (const vfloat4*)in, (vfloat4*)out, n4);

    const int tail_start = n4 * 4;
    const int tail = n - tail_start;
    if (tail > 0) {
        spence_tail_kernel<<<(tail + block - 1) / block, block, 0, stream>>>(
            in, out, tail_start, n);
    }
}